// Round 1
// baseline (2130.186 us; speedup 1.0000x reference)
//
#include <hip/hip_runtime.h>
#include <hip/hip_bf16.h>

#define IN_F 128
#define OUT_F 64

typedef __hip_bfloat16 bf16;

// ---------------- utility: zero a float buffer ----------------
__global__ __launch_bounds__(256) void zero_f32(float* __restrict__ p, int n) {
    int i = blockIdx.x * 256 + threadIdx.x;
    if (i < n) p[i] = 0.0f;
}

// ---------------- degree count (float, for later division) ----------------
__global__ __launch_bounds__(256) void deg_count(const int* __restrict__ dst,
                                                 float* __restrict__ deg, int E) {
    int i = blockIdx.x * 256 + threadIdx.x;
    if (i < E) atomicAdd(&deg[dst[i]], 1.0f);
}

// ---------------- projection: Y[rows x 64] (bf16) = X[rows x 128] @ W[128 x 64]
// 16 rows per 256-thread block; each thread computes 4 (row, col) outputs so
// each W load is reused 4x. rows are always a multiple of 16 (100000/200000/50000/8000).
__global__ __launch_bounds__(256) void proj16(const float* __restrict__ X,
                                              const float* __restrict__ W,
                                              bf16* __restrict__ Y) {
    __shared__ float xs[16 * IN_F];
    const int tid = threadIdx.x;
    const size_t rowBase = (size_t)blockIdx.x * 16;
    const float4* X4 = (const float4*)(X + rowBase * IN_F);
    float4* xs4 = (float4*)xs;
    xs4[tid] = X4[tid];
    xs4[tid + 256] = X4[tid + 256];
    __syncthreads();
    const int col = tid & 63;
    const int r0 = tid >> 6;  // 0..3
    float a0 = 0.f, a1 = 0.f, a2 = 0.f, a3 = 0.f;
    #pragma unroll 8
    for (int k = 0; k < IN_F; k++) {
        float w = W[k * OUT_F + col];       // coalesced 256B across wave, L1-hot
        a0 += xs[(r0 + 0) * IN_F + k] * w;  // LDS broadcast reads (conflict-free)
        a1 += xs[(r0 + 4) * IN_F + k] * w;
        a2 += xs[(r0 + 8) * IN_F + k] * w;
        a3 += xs[(r0 + 12) * IN_F + k] * w;
    }
    bf16* Yb = Y + rowBase * OUT_F;
    Yb[(r0 + 0) * OUT_F + col]  = __float2bfloat16(a0);
    Yb[(r0 + 4) * OUT_F + col]  = __float2bfloat16(a1);
    Yb[(r0 + 8) * OUT_F + col]  = __float2bfloat16(a2);
    Yb[(r0 + 12) * OUT_F + col] = __float2bfloat16(a3);
}

// ---------------- self-loop init: Out[rows x 64] (f32) = X @ W + bias ----------------
__global__ __launch_bounds__(256) void selfloop16(const float* __restrict__ X,
                                                  const float* __restrict__ W,
                                                  const float* __restrict__ bias,
                                                  float* __restrict__ Out) {
    __shared__ float xs[16 * IN_F];
    const int tid = threadIdx.x;
    const size_t rowBase = (size_t)blockIdx.x * 16;
    const float4* X4 = (const float4*)(X + rowBase * IN_F);
    float4* xs4 = (float4*)xs;
    xs4[tid] = X4[tid];
    xs4[tid + 256] = X4[tid + 256];
    __syncthreads();
    const int col = tid & 63;
    const int r0 = tid >> 6;
    float a0 = 0.f, a1 = 0.f, a2 = 0.f, a3 = 0.f;
    #pragma unroll 8
    for (int k = 0; k < IN_F; k++) {
        float w = W[k * OUT_F + col];
        a0 += xs[(r0 + 0) * IN_F + k] * w;
        a1 += xs[(r0 + 4) * IN_F + k] * w;
        a2 += xs[(r0 + 8) * IN_F + k] * w;
        a3 += xs[(r0 + 12) * IN_F + k] * w;
    }
    const float b = bias[col];
    float* Ob = Out + rowBase * OUT_F;
    Ob[(r0 + 0) * OUT_F + col]  = a0 + b;
    Ob[(r0 + 4) * OUT_F + col]  = a1 + b;
    Ob[(r0 + 8) * OUT_F + col]  = a2 + b;
    Ob[(r0 + 12) * OUT_F + col] = a3 + b;
}

// ---------------- edge scatter: one wave per edge, lane = feature ----------------
__global__ __launch_bounds__(256) void scatter_edges(const bf16* __restrict__ Y,
                                                     const int* __restrict__ src,
                                                     const int* __restrict__ dst,
                                                     const float* __restrict__ deg,
                                                     float* __restrict__ out, int E) {
    int gt = blockIdx.x * 256 + threadIdx.x;
    int e = gt >> 6;
    if (e >= E) return;
    int lane = gt & 63;
    int s = src[e];   // same address across wave -> broadcast
    int d = dst[e];
    float inv = 1.0f / fmaxf(deg[d], 1.0f);
    float v = __bfloat162float(Y[(size_t)s * OUT_F + lane]) * inv;
    atomicAdd(&out[(size_t)d * OUT_F + lane], v);
}

// ---------------- final relu ----------------
__global__ __launch_bounds__(256) void relu_inplace(float* __restrict__ p, int n) {
    int i = blockIdx.x * 256 + threadIdx.x;
    if (i < n) p[i] = fmaxf(p[i], 0.0f);
}

extern "C" void kernel_launch(void* const* d_in, const int* in_sizes, int n_in,
                              void* d_out, int out_size, void* d_ws, size_t ws_size,
                              hipStream_t stream) {
    (void)in_sizes; (void)n_in; (void)ws_size;

    const float* x_author = (const float*)d_in[0];
    const float* x_field  = (const float*)d_in[1];
    const float* x_inst   = (const float*)d_in[2];
    const float* x_paper  = (const float*)d_in[3];
    const float* weight   = (const float*)d_in[4];   // [7,128,64]
    const float* slw      = (const float*)d_in[5];   // [128,64]
    const float* bias     = (const float*)d_in[6];   // [64]
    float* out = (float*)d_out;

    const int N_AUTHOR = 100000, N_PAPER = 200000, N_FIELD = 50000, N_INST = 8000;
    const long OUT_AUTHOR = 0;
    const long OUT_FIELD  = (long)N_AUTHOR * OUT_F;                 // 6,400,000
    const long OUT_INST   = OUT_FIELD + (long)N_FIELD * OUT_F;      // 9,600,000
    const long OUT_PAPER  = OUT_INST + (long)N_INST * OUT_F;        // 10,112,000

    // workspace layout: y tables (bf16, 858000 x 64) then deg (f32, 858000)
    bf16* y = (bf16*)d_ws;
    const long Y_ROWS = 858000;
    float* deg = (float*)((char*)d_ws + Y_ROWS * OUT_F * sizeof(bf16));
    const int DEG_TOT = 858000;

    struct RelDesc {
        const float* xsrc; int n_src; int wi;
        const int* src; const int* dst; int E;
        long yrow; long dg; long outb;
    };
    const RelDesc rels[7] = {
        { x_author, N_AUTHOR, 0, (const int*)d_in[7],  (const int*)d_in[8],  1000000,      0,      0, OUT_PAPER  }, // writes
        { x_paper,  N_PAPER,  1, (const int*)d_in[9],  (const int*)d_in[10], 1000000, 100000, 200000, OUT_AUTHOR }, // rev_writes
        { x_paper,  N_PAPER,  2, (const int*)d_in[11], (const int*)d_in[12], 1000000, 300000, 300000, OUT_PAPER  }, // cites
        { x_paper,  N_PAPER,  3, (const int*)d_in[13], (const int*)d_in[14],  800000, 500000, 500000, OUT_FIELD  }, // has_topic
        { x_field,  N_FIELD,  4, (const int*)d_in[15], (const int*)d_in[16],  800000, 700000, 550000, OUT_PAPER  }, // rev_has_topic
        { x_author, N_AUTHOR, 5, (const int*)d_in[17], (const int*)d_in[18],  200000, 750000, 750000, OUT_INST   }, // affiliated_with
        { x_inst,   N_INST,   6, (const int*)d_in[19], (const int*)d_in[20],  200000, 850000, 758000, OUT_AUTHOR }, // rev_affiliated_with
    };

    // 1) zero degree buffers, count degrees
    zero_f32<<<(DEG_TOT + 255) / 256, 256, 0, stream>>>(deg, DEG_TOT);
    for (int r = 0; r < 7; r++)
        deg_count<<<(rels[r].E + 255) / 256, 256, 0, stream>>>(rels[r].dst, deg + rels[r].dg, rels[r].E);

    // 2) projections into bf16 y tables
    for (int r = 0; r < 7; r++)
        proj16<<<rels[r].n_src / 16, 256, 0, stream>>>(
            rels[r].xsrc, weight + (size_t)rels[r].wi * IN_F * OUT_F, y + rels[r].yrow * OUT_F);

    // 3) init out = x @ self_loop_W + bias (accumulator base)
    selfloop16<<<N_AUTHOR / 16, 256, 0, stream>>>(x_author, slw, bias, out + OUT_AUTHOR);
    selfloop16<<<N_FIELD  / 16, 256, 0, stream>>>(x_field,  slw, bias, out + OUT_FIELD);
    selfloop16<<<N_INST   / 16, 256, 0, stream>>>(x_inst,   slw, bias, out + OUT_INST);
    selfloop16<<<N_PAPER  / 16, 256, 0, stream>>>(x_paper,  slw, bias, out + OUT_PAPER);

    // 4) scatter normalized messages (atomic adds into out)
    for (int r = 0; r < 7; r++)
        scatter_edges<<<rels[r].E / 4, 256, 0, stream>>>(
            y + rels[r].yrow * OUT_F, rels[r].src, rels[r].dst,
            deg + rels[r].dg, out + rels[r].outb, rels[r].E);

    // 5) relu in place
    relu_inplace<<<(out_size + 255) / 256, 256, 0, stream>>>(out, out_size);
}

// Round 2
// 1644.182 us; speedup vs baseline: 1.2956x; 1.2956x over previous
//
#include <hip/hip_runtime.h>
#include <hip/hip_bf16.h>

#define IN_F 128
#define OUT_F 64

typedef __hip_bfloat16 bf16;

// ================= degree count (int) =================
__global__ __launch_bounds__(256) void deg_count_i(const int* __restrict__ dst,
                                                   int* __restrict__ deg, int E) {
    int i = blockIdx.x * 256 + threadIdx.x;
    if (i < E) atomicAdd(&deg[dst[i]], 1);
}

// ================= 3-phase exclusive scan over n ints (1024 elems / block) ====
__global__ __launch_bounds__(256) void scan1(const int* __restrict__ deg,
                                             int* __restrict__ off,
                                             int* __restrict__ bsums, int n) {
    __shared__ int ts[256];
    const int tid = threadIdx.x;
    const int base = blockIdx.x * 1024 + tid * 4;
    int4 v = {0, 0, 0, 0};
    if (base < n) v = *(const int4*)(deg + base);   // n % 4 == 0 always here
    int sum = v.x + v.y + v.z + v.w;
    ts[tid] = sum;
    __syncthreads();
    for (int o = 1; o < 256; o <<= 1) {
        int t = (tid >= o) ? ts[tid - o] : 0;
        __syncthreads();
        ts[tid] += t;
        __syncthreads();
    }
    int pre = ts[tid] - sum;   // exclusive prefix of this thread within block
    if (base < n) {
        int4 e;
        e.x = pre;
        e.y = pre + v.x;
        e.z = pre + v.x + v.y;
        e.w = pre + v.x + v.y + v.z;
        *(int4*)(off + base) = e;
    }
    if (tid == 255) bsums[blockIdx.x] = ts[255];
}

__global__ __launch_bounds__(1024) void scan2(int* __restrict__ bsums, int nb) {
    __shared__ int ts[1024];
    const int tid = threadIdx.x;
    int v = (tid < nb) ? bsums[tid] : 0;
    ts[tid] = v;
    __syncthreads();
    for (int o = 1; o < 1024; o <<= 1) {
        int t = (tid >= o) ? ts[tid - o] : 0;
        __syncthreads();
        ts[tid] += t;
        __syncthreads();
    }
    if (tid < nb) bsums[tid] = ts[tid] - v;   // exclusive
}

// adds block prefix; writes BOTH final offsets and the cursor copy; one thread
// writes the sentinel off[n] = E_total.
__global__ __launch_bounds__(256) void scan3(int* __restrict__ off,
                                             int* __restrict__ cursor,
                                             const int* __restrict__ bsums,
                                             int n, int e_total) {
    const int tid = threadIdx.x;
    const int base = blockIdx.x * 1024 + tid * 4;
    const int bp = bsums[blockIdx.x];
    if (base < n) {
        int4 v = *(const int4*)(off + base);
        v.x += bp; v.y += bp; v.z += bp; v.w += bp;
        *(int4*)(off + base) = v;
        *(int4*)(cursor + base) = v;
    }
    if (blockIdx.x == 0 && tid == 0) off[n] = e_total;
}

// ================= CSR fill =================
__global__ __launch_bounds__(256) void fill_csr(const int* __restrict__ src,
                                                const int* __restrict__ dst,
                                                int* __restrict__ cursor,
                                                int* __restrict__ csr, int E) {
    int i = blockIdx.x * 256 + threadIdx.x;
    if (i < E) {
        int p = atomicAdd(&cursor[dst[i]], 1);
        csr[p] = src[i];
    }
}

// ================= projection: Y (bf16) = X @ W, 16 rows/block =================
__global__ __launch_bounds__(256) void proj16(const float* __restrict__ X,
                                              const float* __restrict__ W,
                                              bf16* __restrict__ Y) {
    __shared__ float xs[16 * IN_F];
    const int tid = threadIdx.x;
    const size_t rowBase = (size_t)blockIdx.x * 16;
    const float4* X4 = (const float4*)(X + rowBase * IN_F);
    float4* xs4 = (float4*)xs;
    xs4[tid] = X4[tid];
    xs4[tid + 256] = X4[tid + 256];
    __syncthreads();
    const int col = tid & 63;
    const int r0 = tid >> 6;
    float a0 = 0.f, a1 = 0.f, a2 = 0.f, a3 = 0.f;
    #pragma unroll 8
    for (int k = 0; k < IN_F; k++) {
        float w = W[k * OUT_F + col];
        a0 += xs[(r0 + 0) * IN_F + k] * w;
        a1 += xs[(r0 + 4) * IN_F + k] * w;
        a2 += xs[(r0 + 8) * IN_F + k] * w;
        a3 += xs[(r0 + 12) * IN_F + k] * w;
    }
    bf16* Yb = Y + rowBase * OUT_F;
    Yb[(r0 + 0) * OUT_F + col]  = __float2bfloat16(a0);
    Yb[(r0 + 4) * OUT_F + col]  = __float2bfloat16(a1);
    Yb[(r0 + 8) * OUT_F + col]  = __float2bfloat16(a2);
    Yb[(r0 + 12) * OUT_F + col] = __float2bfloat16(a3);
}

// ================= self-loop init: Out = X @ Wself + bias =================
__global__ __launch_bounds__(256) void selfloop16(const float* __restrict__ X,
                                                  const float* __restrict__ W,
                                                  const float* __restrict__ bias,
                                                  float* __restrict__ Out) {
    __shared__ float xs[16 * IN_F];
    const int tid = threadIdx.x;
    const size_t rowBase = (size_t)blockIdx.x * 16;
    const float4* X4 = (const float4*)(X + rowBase * IN_F);
    float4* xs4 = (float4*)xs;
    xs4[tid] = X4[tid];
    xs4[tid + 256] = X4[tid + 256];
    __syncthreads();
    const int col = tid & 63;
    const int r0 = tid >> 6;
    float a0 = 0.f, a1 = 0.f, a2 = 0.f, a3 = 0.f;
    #pragma unroll 8
    for (int k = 0; k < IN_F; k++) {
        float w = W[k * OUT_F + col];
        a0 += xs[(r0 + 0) * IN_F + k] * w;
        a1 += xs[(r0 + 4) * IN_F + k] * w;
        a2 += xs[(r0 + 8) * IN_F + k] * w;
        a3 += xs[(r0 + 12) * IN_F + k] * w;
    }
    const float b = bias[col];
    float* Ob = Out + rowBase * OUT_F;
    Ob[(r0 + 0) * OUT_F + col]  = a0 + b;
    Ob[(r0 + 4) * OUT_F + col]  = a1 + b;
    Ob[(r0 + 8) * OUT_F + col]  = a2 + b;
    Ob[(r0 + 12) * OUT_F + col] = a3 + b;
}

// ================= fused gather: wave per node, up to 3 relations ============
// acc = sum_r ( sum_{e in csr_r(n)} y_r[src_e] ) / max(deg_r(n),1)
// out = relu(out_prewritten + acc); single coalesced write per node.
template <int NR>
__global__ __launch_bounds__(256) void gather_fused(
    const int* __restrict__ csr,
    const int* __restrict__ off0, const bf16* __restrict__ y0,
    const int* __restrict__ off1, const bf16* __restrict__ y1,
    const int* __restrict__ off2, const bf16* __restrict__ y2,
    float* __restrict__ out) {
    const int tid = threadIdx.x;
    const int lane = tid & 63;
    const int n = blockIdx.x * 4 + (tid >> 6);
    const int* offs[3] = {off0, off1, off2};
    const bf16* ys[3]  = {y0, y1, y2};
    float acc = 0.f;
    #pragma unroll
    for (int r = 0; r < NR; r++) {
        const int s = offs[r][n];
        const int e = offs[r][n + 1];
        const bf16* __restrict__ yr = ys[r];
        float racc = 0.f;
        int j = s;
        // 2-edge unroll: two independent y-row loads in flight
        for (; j + 1 < e; j += 2) {
            int c0 = csr[j];
            int c1 = csr[j + 1];
            float v0 = __bfloat162float(yr[(size_t)c0 * OUT_F + lane]);
            float v1 = __bfloat162float(yr[(size_t)c1 * OUT_F + lane]);
            racc += v0 + v1;
        }
        if (j < e) {
            int c0 = csr[j];
            racc += __bfloat162float(yr[(size_t)c0 * OUT_F + lane]);
        }
        int dg = e - s;
        acc += racc / (float)(dg > 1 ? dg : 1);
    }
    size_t o = (size_t)n * OUT_F + lane;
    out[o] = fmaxf(out[o] + acc, 0.f);
}

extern "C" void kernel_launch(void* const* d_in, const int* in_sizes, int n_in,
                              void* d_out, int out_size, void* d_ws, size_t ws_size,
                              hipStream_t stream) {
    (void)in_sizes; (void)n_in; (void)ws_size; (void)out_size;

    const float* x_author = (const float*)d_in[0];
    const float* x_field  = (const float*)d_in[1];
    const float* x_inst   = (const float*)d_in[2];
    const float* x_paper  = (const float*)d_in[3];
    const float* weight   = (const float*)d_in[4];   // [7,128,64]
    const float* slw      = (const float*)d_in[5];   // [128,64]
    const float* bias     = (const float*)d_in[6];   // [64]
    float* out = (float*)d_out;

    const int N_AUTHOR = 100000, N_PAPER = 200000, N_FIELD = 50000, N_INST = 8000;
    const int N_NODES = 858000;            // sum of per-relation dst segments
    const int E_TOTAL = 5000000;
    const long OUT_AUTHOR = 0;
    const long OUT_FIELD  = (long)N_AUTHOR * OUT_F;
    const long OUT_INST   = OUT_FIELD + (long)N_FIELD * OUT_F;
    const long OUT_PAPER  = OUT_INST + (long)N_INST * OUT_F;

    // ---- workspace layout (all 128B aligned) ----
    char* w = (char*)d_ws;
    auto alignup = [](size_t v) { return (v + 127) & ~(size_t)127; };
    bf16* y = (bf16*)w;                     size_t o1 = alignup((size_t)N_NODES * OUT_F * sizeof(bf16));
    int* deg    = (int*)(w + o1);           size_t o2 = o1 + alignup((size_t)N_NODES * sizeof(int));
    int* off    = (int*)(w + o2);           size_t o3 = o2 + alignup(((size_t)N_NODES + 4) * sizeof(int));
    int* cursor = (int*)(w + o3);           size_t o4 = o3 + alignup((size_t)N_NODES * sizeof(int));
    int* csr    = (int*)(w + o4);           size_t o5 = o4 + alignup((size_t)E_TOTAL * sizeof(int));
    int* bsums  = (int*)(w + o5);

    struct RelDesc {
        const float* xsrc; int n_src; int wi;
        const int* src; const int* dst; int E;
        long yrow;   // row base into y table
        int  dg;     // base into deg/off/cursor segments
    };
    const RelDesc rels[7] = {
        { x_author, N_AUTHOR, 0, (const int*)d_in[7],  (const int*)d_in[8],  1000000,      0,      0 }, // writes -> paper
        { x_paper,  N_PAPER,  1, (const int*)d_in[9],  (const int*)d_in[10], 1000000, 100000, 200000 }, // rev_writes -> author
        { x_paper,  N_PAPER,  2, (const int*)d_in[11], (const int*)d_in[12], 1000000, 300000, 300000 }, // cites -> paper
        { x_paper,  N_PAPER,  3, (const int*)d_in[13], (const int*)d_in[14],  800000, 500000, 500000 }, // has_topic -> field
        { x_field,  N_FIELD,  4, (const int*)d_in[15], (const int*)d_in[16],  800000, 700000, 550000 }, // rev_has_topic -> paper
        { x_author, N_AUTHOR, 5, (const int*)d_in[17], (const int*)d_in[18],  200000, 750000, 750000 }, // affiliated_with -> inst
        { x_inst,   N_INST,   6, (const int*)d_in[19], (const int*)d_in[20],  200000, 850000, 758000 }, // rev_affiliated_with -> author
    };

    const int NBLK = (N_NODES + 1023) / 1024;   // 838

    // ---- 1) degrees ----
    hipMemsetAsync(deg, 0, (size_t)N_NODES * sizeof(int), stream);
    for (int r = 0; r < 7; r++)
        deg_count_i<<<(rels[r].E + 255) / 256, 256, 0, stream>>>(rels[r].dst, deg + rels[r].dg, rels[r].E);

    // ---- 2) exclusive scan -> off, cursor ----
    scan1<<<NBLK, 256, 0, stream>>>(deg, off, bsums, N_NODES);
    scan2<<<1, 1024, 0, stream>>>(bsums, NBLK);
    scan3<<<NBLK, 256, 0, stream>>>(off, cursor, bsums, N_NODES, E_TOTAL);

    // ---- 3) CSR fill ----
    for (int r = 0; r < 7; r++)
        fill_csr<<<(rels[r].E + 255) / 256, 256, 0, stream>>>(
            rels[r].src, rels[r].dst, cursor + rels[r].dg, csr, rels[r].E);

    // ---- 4) projections into bf16 y tables ----
    for (int r = 0; r < 7; r++)
        proj16<<<rels[r].n_src / 16, 256, 0, stream>>>(
            rels[r].xsrc, weight + (size_t)rels[r].wi * IN_F * OUT_F, y + rels[r].yrow * OUT_F);

    // ---- 5) self-loop init of out ----
    selfloop16<<<N_AUTHOR / 16, 256, 0, stream>>>(x_author, slw, bias, out + OUT_AUTHOR);
    selfloop16<<<N_FIELD  / 16, 256, 0, stream>>>(x_field,  slw, bias, out + OUT_FIELD);
    selfloop16<<<N_INST   / 16, 256, 0, stream>>>(x_inst,   slw, bias, out + OUT_INST);
    selfloop16<<<N_PAPER  / 16, 256, 0, stream>>>(x_paper,  slw, bias, out + OUT_PAPER);

    // ---- 6) fused gather + norm + selfloop-add + relu ----
    // paper: writes(0), cites(2), rev_has_topic(4)
    gather_fused<3><<<N_PAPER / 4, 256, 0, stream>>>(
        csr,
        off + 0,      y + (long)rels[0].yrow * OUT_F,
        off + 300000, y + (long)rels[2].yrow * OUT_F,
        off + 550000, y + (long)rels[4].yrow * OUT_F,
        out + OUT_PAPER);
    // author: rev_writes(1), rev_affiliated_with(6)
    gather_fused<2><<<N_AUTHOR / 4, 256, 0, stream>>>(
        csr,
        off + 200000, y + (long)rels[1].yrow * OUT_F,
        off + 758000, y + (long)rels[6].yrow * OUT_F,
        nullptr, nullptr,
        out + OUT_AUTHOR);
    // field: has_topic(3)
    gather_fused<1><<<N_FIELD / 4, 256, 0, stream>>>(
        csr,
        off + 500000, y + (long)rels[3].yrow * OUT_F,
        nullptr, nullptr, nullptr, nullptr,
        out + OUT_FIELD);
    // inst: affiliated_with(5)
    gather_fused<1><<<N_INST / 4, 256, 0, stream>>>(
        csr,
        off + 750000, y + (long)rels[5].yrow * OUT_F,
        nullptr, nullptr, nullptr, nullptr,
        out + OUT_INST);
}

// Round 3
// 1298.763 us; speedup vs baseline: 1.6402x; 1.2660x over previous
//
#include <hip/hip_runtime.h>
#include <hip/hip_bf16.h>

#define IN_F 128
#define OUT_F 64

typedef __hip_bfloat16 bf16;
typedef __attribute__((ext_vector_type(8))) short short8;
typedef __attribute__((ext_vector_type(4))) float f32x4;

__device__ inline short f2bf(float f) {
    __hip_bfloat16 h = __float2bfloat16(f);
    return __builtin_bit_cast(short, h);
}
__device__ inline float bflo(unsigned u) {  // low bf16 of a uint -> float
    unsigned v = u << 16;
    return __builtin_bit_cast(float, v);
}
__device__ inline float bfhi(unsigned u) {  // high bf16 of a uint -> float
    unsigned v = u & 0xFFFF0000u;
    return __builtin_bit_cast(float, v);
}

// ================= degree count (int) =================
__global__ __launch_bounds__(256) void deg_count_i(const int* __restrict__ dst,
                                                   int* __restrict__ deg, int E) {
    int i = blockIdx.x * 256 + threadIdx.x;
    if (i < E) atomicAdd(&deg[dst[i]], 1);
}

// ================= 3-phase exclusive scan (1024 elems / block) ================
__global__ __launch_bounds__(256) void scan1(const int* __restrict__ deg,
                                             int* __restrict__ off,
                                             int* __restrict__ bsums, int n) {
    __shared__ int ts[256];
    const int tid = threadIdx.x;
    const int base = blockIdx.x * 1024 + tid * 4;
    int4 v = {0, 0, 0, 0};
    if (base < n) v = *(const int4*)(deg + base);
    int sum = v.x + v.y + v.z + v.w;
    ts[tid] = sum;
    __syncthreads();
    for (int o = 1; o < 256; o <<= 1) {
        int t = (tid >= o) ? ts[tid - o] : 0;
        __syncthreads();
        ts[tid] += t;
        __syncthreads();
    }
    int pre = ts[tid] - sum;
    if (base < n) {
        int4 e;
        e.x = pre;
        e.y = pre + v.x;
        e.z = pre + v.x + v.y;
        e.w = pre + v.x + v.y + v.z;
        *(int4*)(off + base) = e;
    }
    if (tid == 255) bsums[blockIdx.x] = ts[255];
}

__global__ __launch_bounds__(1024) void scan2(int* __restrict__ bsums, int nb) {
    __shared__ int ts[1024];
    const int tid = threadIdx.x;
    int v = (tid < nb) ? bsums[tid] : 0;
    ts[tid] = v;
    __syncthreads();
    for (int o = 1; o < 1024; o <<= 1) {
        int t = (tid >= o) ? ts[tid - o] : 0;
        __syncthreads();
        ts[tid] += t;
        __syncthreads();
    }
    if (tid < nb) bsums[tid] = ts[tid] - v;
}

__global__ __launch_bounds__(256) void scan3(int* __restrict__ off,
                                             int* __restrict__ cursor,
                                             const int* __restrict__ bsums,
                                             int n, int e_total) {
    const int tid = threadIdx.x;
    const int base = blockIdx.x * 1024 + tid * 4;
    const int bp = bsums[blockIdx.x];
    if (base < n) {
        int4 v = *(const int4*)(off + base);
        v.x += bp; v.y += bp; v.z += bp; v.w += bp;
        *(int4*)(off + base) = v;
        *(int4*)(cursor + base) = v;
    }
    if (blockIdx.x == 0 && tid == 0) off[n] = e_total;
}

// ================= CSR fill =================
__global__ __launch_bounds__(256) void fill_csr(const int* __restrict__ src,
                                                const int* __restrict__ dst,
                                                int* __restrict__ cursor,
                                                int* __restrict__ csr, int E) {
    int i = blockIdx.x * 256 + threadIdx.x;
    if (i < E) {
        int p = atomicAdd(&cursor[dst[i]], 1);
        csr[p] = src[i];
    }
}

// ================= W prep: 8 matrices f32[128][64] -> bf16 Wt[64][128] ========
__global__ __launch_bounds__(256) void prep_wt(const float* __restrict__ W7,
                                               const float* __restrict__ slw,
                                               short* __restrict__ Wt) {
    const int mat = blockIdx.x;  // 0..7 (7 == self-loop)
    const float* Ws = (mat < 7) ? (W7 + (size_t)mat * IN_F * OUT_F) : slw;
    short* Wo = Wt + (size_t)mat * IN_F * OUT_F;
    for (int i = threadIdx.x; i < IN_F * OUT_F; i += 256) {
        int n = i >> 7;          // 0..63
        int k = i & 127;         // 0..127
        Wo[i] = f2bf(Ws[k * OUT_F + n]);   // Wt[n][k] = W[k][n]
    }
}

// ================= fused MFMA projection =====================================
// Per block: 16 rows of X (f32[128]); 4 waves each own a 16-col slab of N=64.
// Computes R relation projections (bf16 out) + self-loop (+bias, f32 out).
// MFMA 16x16x32 bf16: A[m=lane&15][k=quad*8+j]; B[k=quad*8+j][n=lane&15];
// C/D: col=lane&15, row=quad*4+reg.
template <int R>
__global__ __launch_bounds__(256) void proj_mfma(
    const float* __restrict__ X,
    const short* __restrict__ wt0, const short* __restrict__ wt1,
    const short* __restrict__ wt2, const short* __restrict__ wtS,
    const float* __restrict__ bias,
    bf16* __restrict__ Y0, bf16* __restrict__ Y1, bf16* __restrict__ Y2,
    float* __restrict__ OutSelf) {
    const int tid = threadIdx.x;
    const int wave = tid >> 6;
    const int lane = tid & 63;
    const int m = lane & 15;
    const int quad = lane >> 4;
    const int rowBase = blockIdx.x * 16;
    const int ncol = wave * 16 + m;

    // ---- A fragments: rows rowBase+m, k = quad*8 + kb*32 + j (f32 -> bf16)
    short8 af[4];
    const float* xrow = X + (size_t)(rowBase + m) * IN_F + quad * 8;
    #pragma unroll
    for (int kb = 0; kb < 4; kb++) {
        float4 x0 = *(const float4*)(xrow + kb * 32);
        float4 x1 = *(const float4*)(xrow + kb * 32 + 4);
        short8 a;
        a[0] = f2bf(x0.x); a[1] = f2bf(x0.y); a[2] = f2bf(x0.z); a[3] = f2bf(x0.w);
        a[4] = f2bf(x1.x); a[5] = f2bf(x1.y); a[6] = f2bf(x1.z); a[7] = f2bf(x1.w);
        af[kb] = a;
    }

    const short* wts[3] = {wt0, wt1, wt2};
    bf16* Ys[3] = {Y0, Y1, Y2};

    // ---- relation projections
    #pragma unroll
    for (int r = 0; r < R; r++) {
        const short* wrow = wts[r] + (size_t)ncol * IN_F + quad * 8;
        f32x4 acc = {0.f, 0.f, 0.f, 0.f};
        #pragma unroll
        for (int kb = 0; kb < 4; kb++) {
            short8 bfar = *(const short8*)(wrow + kb * 32);
            acc = __builtin_amdgcn_mfma_f32_16x16x32_bf16(af[kb], bfar, acc, 0, 0, 0);
        }
        bf16* Yr = Ys[r];
        #pragma unroll
        for (int reg = 0; reg < 4; reg++) {
            int row = rowBase + quad * 4 + reg;
            Yr[(size_t)row * OUT_F + ncol] = __float2bfloat16(acc[reg]);
        }
    }

    // ---- self loop + bias
    {
        const short* wrow = wtS + (size_t)ncol * IN_F + quad * 8;
        f32x4 acc = {0.f, 0.f, 0.f, 0.f};
        #pragma unroll
        for (int kb = 0; kb < 4; kb++) {
            short8 bfar = *(const short8*)(wrow + kb * 32);
            acc = __builtin_amdgcn_mfma_f32_16x16x32_bf16(af[kb], bfar, acc, 0, 0, 0);
        }
        const float b = bias[ncol];
        #pragma unroll
        for (int reg = 0; reg < 4; reg++) {
            int row = rowBase + quad * 4 + reg;
            OutSelf[(size_t)row * OUT_F + ncol] = acc[reg] + b;
        }
    }
}

// ================= gather: 16 lanes/edge, 4 edges per instruction =============
// lane: g = lane>>4 (edge subgroup), f4 = lane&15 (feature quad, 4 feats = 8B).
// 2-deep unroll -> 8 edge rows in flight per wave. Butterfly xor16/32 combines
// subgroups; lanes 0..15 do one float4 RMW of out (+relu).
template <int NR>
__global__ __launch_bounds__(256) void gather16(
    const int* __restrict__ csr,
    const int* __restrict__ off0, const bf16* __restrict__ y0,
    const int* __restrict__ off1, const bf16* __restrict__ y1,
    const int* __restrict__ off2, const bf16* __restrict__ y2,
    float* __restrict__ out) {
    const int tid = threadIdx.x;
    const int lane = tid & 63;
    const int n = blockIdx.x * 4 + (tid >> 6);
    const int g = lane >> 4;
    const int f4 = lane & 15;
    const int* offs[3] = {off0, off1, off2};
    const bf16* ys[3] = {y0, y1, y2};
    float4 acc = {0.f, 0.f, 0.f, 0.f};
    #pragma unroll
    for (int r = 0; r < NR; r++) {
        const int s = offs[r][n];
        const int e = offs[r][n + 1];
        const uint2* yr = (const uint2*)ys[r];
        float4 racc = {0.f, 0.f, 0.f, 0.f};
        for (int j = s; j < e; j += 8) {
            int j0 = j + g;
            int j1 = j + g + 4;
            bool v0 = j0 < e, v1 = j1 < e;
            int c0 = v0 ? csr[j0] : 0;
            int c1 = v1 ? csr[j1] : 0;
            if (v0) {
                uint2 u = yr[(size_t)c0 * 16 + f4];
                racc.x += bflo(u.x); racc.y += bfhi(u.x);
                racc.z += bflo(u.y); racc.w += bfhi(u.y);
            }
            if (v1) {
                uint2 u = yr[(size_t)c1 * 16 + f4];
                racc.x += bflo(u.x); racc.y += bfhi(u.x);
                racc.z += bflo(u.y); racc.w += bfhi(u.y);
            }
        }
        int dg = e - s;
        float inv = 1.0f / (float)(dg > 1 ? dg : 1);
        acc.x += racc.x * inv; acc.y += racc.y * inv;
        acc.z += racc.z * inv; acc.w += racc.w * inv;
    }
    // combine the 4 edge-subgroups
    #pragma unroll
    for (int d = 16; d <= 32; d <<= 1) {
        acc.x += __shfl_xor(acc.x, d, 64);
        acc.y += __shfl_xor(acc.y, d, 64);
        acc.z += __shfl_xor(acc.z, d, 64);
        acc.w += __shfl_xor(acc.w, d, 64);
    }
    if (lane < 16) {
        float4* o4 = (float4*)(out + (size_t)n * OUT_F);
        float4 cur = o4[lane];
        cur.x = fmaxf(cur.x + acc.x, 0.f);
        cur.y = fmaxf(cur.y + acc.y, 0.f);
        cur.z = fmaxf(cur.z + acc.z, 0.f);
        cur.w = fmaxf(cur.w + acc.w, 0.f);
        o4[lane] = cur;
    }
}

extern "C" void kernel_launch(void* const* d_in, const int* in_sizes, int n_in,
                              void* d_out, int out_size, void* d_ws, size_t ws_size,
                              hipStream_t stream) {
    (void)in_sizes; (void)n_in; (void)ws_size; (void)out_size;

    const float* x_author = (const float*)d_in[0];
    const float* x_field  = (const float*)d_in[1];
    const float* x_inst   = (const float*)d_in[2];
    const float* x_paper  = (const float*)d_in[3];
    const float* weight   = (const float*)d_in[4];   // [7,128,64]
    const float* slw      = (const float*)d_in[5];   // [128,64]
    const float* bias     = (const float*)d_in[6];   // [64]
    float* out = (float*)d_out;

    const int N_AUTHOR = 100000, N_PAPER = 200000, N_FIELD = 50000, N_INST = 8000;
    const int N_NODES = 858000;
    const int E_TOTAL = 5000000;
    const long OUT_AUTHOR = 0;
    const long OUT_FIELD  = (long)N_AUTHOR * OUT_F;
    const long OUT_INST   = OUT_FIELD + (long)N_FIELD * OUT_F;
    const long OUT_PAPER  = OUT_INST + (long)N_INST * OUT_F;

    // ---- workspace layout ----
    char* w = (char*)d_ws;
    auto alignup = [](size_t v) { return (v + 127) & ~(size_t)127; };
    bf16* y  = (bf16*)w;              size_t o1 = alignup((size_t)N_NODES * OUT_F * sizeof(bf16));
    int* deg = (int*)(w + o1);        size_t o2 = o1 + alignup((size_t)N_NODES * sizeof(int));
    int* off = (int*)(w + o2);        size_t o3 = o2 + alignup(((size_t)N_NODES + 4) * sizeof(int));
    int* cursor = (int*)(w + o3);     size_t o4 = o3 + alignup((size_t)N_NODES * sizeof(int));
    int* csr = (int*)(w + o4);        size_t o5 = o4 + alignup((size_t)E_TOTAL * sizeof(int));
    int* bsums = (int*)(w + o5);      size_t o6 = o5 + alignup(2048 * sizeof(int));
    short* wt = (short*)(w + o6);     // 8 * 8192 bf16

    struct RelDesc {
        const float* xsrc; int n_src; int wi;
        const int* src; const int* dst; int E;
        long yrow; int dg;
    };
    const RelDesc rels[7] = {
        { x_author, N_AUTHOR, 0, (const int*)d_in[7],  (const int*)d_in[8],  1000000,      0,      0 }, // writes -> paper
        { x_paper,  N_PAPER,  1, (const int*)d_in[9],  (const int*)d_in[10], 1000000, 100000, 200000 }, // rev_writes -> author
        { x_paper,  N_PAPER,  2, (const int*)d_in[11], (const int*)d_in[12], 1000000, 300000, 300000 }, // cites -> paper
        { x_paper,  N_PAPER,  3, (const int*)d_in[13], (const int*)d_in[14],  800000, 500000, 500000 }, // has_topic -> field
        { x_field,  N_FIELD,  4, (const int*)d_in[15], (const int*)d_in[16],  800000, 700000, 550000 }, // rev_has_topic -> paper
        { x_author, N_AUTHOR, 5, (const int*)d_in[17], (const int*)d_in[18],  200000, 750000, 750000 }, // affiliated_with -> inst
        { x_inst,   N_INST,   6, (const int*)d_in[19], (const int*)d_in[20],  200000, 850000, 758000 }, // rev_affiliated_with -> author
    };

    const int NBLK = (N_NODES + 1023) / 1024;

    // ---- 1) degrees ----
    hipMemsetAsync(deg, 0, (size_t)N_NODES * sizeof(int), stream);
    for (int r = 0; r < 7; r++)
        deg_count_i<<<(rels[r].E + 255) / 256, 256, 0, stream>>>(rels[r].dst, deg + rels[r].dg, rels[r].E);

    // ---- 2) scan -> off, cursor ----
    scan1<<<NBLK, 256, 0, stream>>>(deg, off, bsums, N_NODES);
    scan2<<<1, 1024, 0, stream>>>(bsums, NBLK);
    scan3<<<NBLK, 256, 0, stream>>>(off, cursor, bsums, N_NODES, E_TOTAL);

    // ---- 3) CSR fill ----
    for (int r = 0; r < 7; r++)
        fill_csr<<<(rels[r].E + 255) / 256, 256, 0, stream>>>(
            rels[r].src, rels[r].dst, cursor + rels[r].dg, csr, rels[r].E);

    // ---- 4) W -> bf16 transposed ----
    prep_wt<<<8, 256, 0, stream>>>(weight, slw, wt);

    // ---- 5) fused MFMA projections + self-loop init ----
    const short* WT = wt;
    // paper sources rels 1 (rev_writes), 2 (cites), 3 (has_topic) + self
    proj_mfma<3><<<N_PAPER / 16, 256, 0, stream>>>(
        x_paper, WT + 1 * 8192, WT + 2 * 8192, WT + 3 * 8192, WT + 7 * 8192, bias,
        y + (long)rels[1].yrow * OUT_F, y + (long)rels[2].yrow * OUT_F,
        y + (long)rels[3].yrow * OUT_F, out + OUT_PAPER);
    // author sources rels 0 (writes), 5 (affiliated_with) + self
    proj_mfma<2><<<N_AUTHOR / 16, 256, 0, stream>>>(
        x_author, WT + 0 * 8192, WT + 5 * 8192, nullptr, WT + 7 * 8192, bias,
        y + (long)rels[0].yrow * OUT_F, y + (long)rels[5].yrow * OUT_F,
        nullptr, out + OUT_AUTHOR);
    // field sources rel 4 (rev_has_topic) + self
    proj_mfma<1><<<N_FIELD / 16, 256, 0, stream>>>(
        x_field, WT + 4 * 8192, nullptr, nullptr, WT + 7 * 8192, bias,
        y + (long)rels[4].yrow * OUT_F, nullptr, nullptr, out + OUT_FIELD);
    // inst sources rel 6 (rev_affiliated_with) + self
    proj_mfma<1><<<N_INST / 16, 256, 0, stream>>>(
        x_inst, WT + 6 * 8192, nullptr, nullptr, WT + 7 * 8192, bias,
        y + (long)rels[6].yrow * OUT_F, nullptr, nullptr, out + OUT_INST);

    // ---- 6) fused gather + norm + selfloop-add + relu ----
    // paper: writes(0), cites(2), rev_has_topic(4)
    gather16<3><<<N_PAPER / 4, 256, 0, stream>>>(
        csr,
        off + 0,      y + (long)rels[0].yrow * OUT_F,
        off + 300000, y + (long)rels[2].yrow * OUT_F,
        off + 550000, y + (long)rels[4].yrow * OUT_F,
        out + OUT_PAPER);
    // author: rev_writes(1), rev_affiliated_with(6)
    gather16<2><<<N_AUTHOR / 4, 256, 0, stream>>>(
        csr,
        off + 200000, y + (long)rels[1].yrow * OUT_F,
        off + 758000, y + (long)rels[6].yrow * OUT_F,
        nullptr, nullptr,
        out + OUT_AUTHOR);
    // field: has_topic(3)
    gather16<1><<<N_FIELD / 4, 256, 0, stream>>>(
        csr,
        off + 500000, y + (long)rels[3].yrow * OUT_F,
        nullptr, nullptr, nullptr, nullptr,
        out + OUT_FIELD);
    // inst: affiliated_with(5)
    gather16<1><<<N_INST / 4, 256, 0, stream>>>(
        csr,
        off + 750000, y + (long)rels[5].yrow * OUT_F,
        nullptr, nullptr, nullptr, nullptr,
        out + OUT_INST);
}

// Round 4
// 1290.759 us; speedup vs baseline: 1.6503x; 1.0062x over previous
//
#include <hip/hip_runtime.h>
#include <hip/hip_bf16.h>

#define IN_F 128
#define OUT_F 64

typedef __hip_bfloat16 bf16;
typedef __attribute__((ext_vector_type(8))) short short8;
typedef __attribute__((ext_vector_type(4))) float f32x4;

// ---------------- problem constants (all compile-time) ----------------
#define N_AUTHOR 100000
#define N_PAPER  200000
#define N_FIELD  50000
#define N_INST   8000
#define N_NODES  858000
#define E_TOTAL  5000000

// output segment bases (floats)
#define OUT_AUTHOR 0L
#define OUT_FIELD  (6400000L)     // N_AUTHOR*64
#define OUT_INST   (9600000L)     // + N_FIELD*64
#define OUT_PAPER  (10112000L)    // + N_INST*64

// deg/off segment bases (per destination of each relation)
#define DG_WRITES   0
#define DG_RWRITES  200000
#define DG_CITES    300000
#define DG_HTOPIC   500000
#define DG_RHTOPIC  550000
#define DG_AFFIL    750000
#define DG_RAFFIL   758000

// y-table row bases (per relation)
#define YR_WRITES   0L
#define YR_RWRITES  100000L
#define YR_CITES    300000L
#define YR_HTOPIC   500000L
#define YR_RHTOPIC  700000L
#define YR_AFFIL    750000L
#define YR_RAFFIL   850000L

__device__ inline short f2bf(float f) {
    __hip_bfloat16 h = __float2bfloat16(f);
    return __builtin_bit_cast(short, h);
}
__device__ inline float bflo(unsigned u) {
    unsigned v = u << 16;
    return __builtin_bit_cast(float, v);
}
__device__ inline float bfhi(unsigned u) {
    unsigned v = u & 0xFFFF0000u;
    return __builtin_bit_cast(float, v);
}

// ================= merged degree count =================
// block ranges per relation: ceil(E/256) blocks each
// 1M->3907, 1M->3907, 1M->3907, 800k->3125, 800k->3125, 200k->782, 200k->782
__device__ __forceinline__ void degSeg(const int* __restrict__ dst, int E,
                                       int* __restrict__ deg, int lb) {
    int i = lb * 256 + (int)threadIdx.x;
    if (i < E) atomicAdd(&deg[dst[i]], 1);
}
__global__ __launch_bounds__(256) void deg_all(
    const int* d0, const int* d1, const int* d2, const int* d3,
    const int* d4, const int* d5, const int* d6, int* __restrict__ deg) {
    int b = blockIdx.x;
    if      (b < 3907)  degSeg(d0, 1000000, deg + DG_WRITES,  b);
    else if (b < 7814)  degSeg(d1, 1000000, deg + DG_RWRITES, b - 3907);
    else if (b < 11721) degSeg(d2, 1000000, deg + DG_CITES,   b - 7814);
    else if (b < 14846) degSeg(d3,  800000, deg + DG_HTOPIC,  b - 11721);
    else if (b < 17971) degSeg(d4,  800000, deg + DG_RHTOPIC, b - 14846);
    else if (b < 18753) degSeg(d5,  200000, deg + DG_AFFIL,   b - 17971);
    else                degSeg(d6,  200000, deg + DG_RAFFIL,  b - 18753);
}

// ================= 3-phase exclusive scan =================
__global__ __launch_bounds__(256) void scan1(const int* __restrict__ deg,
                                             int* __restrict__ off,
                                             int* __restrict__ bsums, int n) {
    __shared__ int ts[256];
    const int tid = threadIdx.x;
    const int base = blockIdx.x * 1024 + tid * 4;
    int4 v = {0, 0, 0, 0};
    if (base < n) v = *(const int4*)(deg + base);
    int sum = v.x + v.y + v.z + v.w;
    ts[tid] = sum;
    __syncthreads();
    for (int o = 1; o < 256; o <<= 1) {
        int t = (tid >= o) ? ts[tid - o] : 0;
        __syncthreads();
        ts[tid] += t;
        __syncthreads();
    }
    int pre = ts[tid] - sum;
    if (base < n) {
        int4 e;
        e.x = pre;
        e.y = pre + v.x;
        e.z = pre + v.x + v.y;
        e.w = pre + v.x + v.y + v.z;
        *(int4*)(off + base) = e;
    }
    if (tid == 255) bsums[blockIdx.x] = ts[255];
}

__global__ __launch_bounds__(1024) void scan2(int* __restrict__ bsums, int nb) {
    __shared__ int ts[1024];
    const int tid = threadIdx.x;
    int v = (tid < nb) ? bsums[tid] : 0;
    ts[tid] = v;
    __syncthreads();
    for (int o = 1; o < 1024; o <<= 1) {
        int t = (tid >= o) ? ts[tid - o] : 0;
        __syncthreads();
        ts[tid] += t;
        __syncthreads();
    }
    if (tid < nb) bsums[tid] = ts[tid] - v;
}

__global__ __launch_bounds__(256) void scan3(int* __restrict__ off,
                                             int* __restrict__ cursor,
                                             const int* __restrict__ bsums,
                                             int n, int e_total) {
    const int tid = threadIdx.x;
    const int base = blockIdx.x * 1024 + tid * 4;
    const int bp = bsums[blockIdx.x];
    if (base < n) {
        int4 v = *(const int4*)(off + base);
        v.x += bp; v.y += bp; v.z += bp; v.w += bp;
        *(int4*)(off + base) = v;
        *(int4*)(cursor + base) = v;
    }
    if (blockIdx.x == 0 && tid == 0) off[n] = e_total;
}

// ================= merged CSR fill =================
__device__ __forceinline__ void fillSeg(const int* __restrict__ src,
                                        const int* __restrict__ dst, int E,
                                        int* __restrict__ cursor,
                                        int* __restrict__ csr, int lb) {
    int i = lb * 256 + (int)threadIdx.x;
    if (i < E) {
        int p = atomicAdd(&cursor[dst[i]], 1);
        csr[p] = src[i];
    }
}
__global__ __launch_bounds__(256) void fill_all(
    const int* s0, const int* d0, const int* s1, const int* d1,
    const int* s2, const int* d2, const int* s3, const int* d3,
    const int* s4, const int* d4, const int* s5, const int* d5,
    const int* s6, const int* d6,
    int* __restrict__ cursor, int* __restrict__ csr) {
    int b = blockIdx.x;
    if      (b < 3907)  fillSeg(s0, d0, 1000000, cursor + DG_WRITES,  csr, b);
    else if (b < 7814)  fillSeg(s1, d1, 1000000, cursor + DG_RWRITES, csr, b - 3907);
    else if (b < 11721) fillSeg(s2, d2, 1000000, cursor + DG_CITES,   csr, b - 7814);
    else if (b < 14846) fillSeg(s3, d3,  800000, cursor + DG_HTOPIC,  csr, b - 11721);
    else if (b < 17971) fillSeg(s4, d4,  800000, cursor + DG_RHTOPIC, csr, b - 14846);
    else if (b < 18753) fillSeg(s5, d5,  200000, cursor + DG_AFFIL,   csr, b - 17971);
    else                fillSeg(s6, d6,  200000, cursor + DG_RAFFIL,  csr, b - 18753);
}

// ================= W prep: 8 matrices f32[128][64] -> bf16 Wt[64][128] ========
__global__ __launch_bounds__(256) void prep_wt(const float* __restrict__ W7,
                                               const float* __restrict__ slw,
                                               short* __restrict__ Wt) {
    const int mat = blockIdx.x;
    const float* Ws = (mat < 7) ? (W7 + (size_t)mat * IN_F * OUT_F) : slw;
    short* Wo = Wt + (size_t)mat * IN_F * OUT_F;
    for (int i = threadIdx.x; i < IN_F * OUT_F; i += 256) {
        int n = i >> 7;
        int k = i & 127;
        Wo[i] = f2bf(Ws[k * OUT_F + n]);
    }
}

// ================= merged MFMA projection =====================================
template <int R>
__device__ __forceinline__ void projBody(
    int blk, const float* __restrict__ X,
    const short* __restrict__ wt0, const short* __restrict__ wt1,
    const short* __restrict__ wt2, const short* __restrict__ wtS,
    const float* __restrict__ bias,
    bf16* __restrict__ Y0, bf16* __restrict__ Y1, bf16* __restrict__ Y2,
    float* __restrict__ OutSelf) {
    const int tid = threadIdx.x;
    const int wave = tid >> 6;
    const int lane = tid & 63;
    const int m = lane & 15;
    const int quad = lane >> 4;
    const int rowBase = blk * 16;
    const int ncol = wave * 16 + m;

    short8 af[4];
    const float* xrow = X + (size_t)(rowBase + m) * IN_F + quad * 8;
    #pragma unroll
    for (int kb = 0; kb < 4; kb++) {
        float4 x0 = *(const float4*)(xrow + kb * 32);
        float4 x1 = *(const float4*)(xrow + kb * 32 + 4);
        short8 a;
        a[0] = f2bf(x0.x); a[1] = f2bf(x0.y); a[2] = f2bf(x0.z); a[3] = f2bf(x0.w);
        a[4] = f2bf(x1.x); a[5] = f2bf(x1.y); a[6] = f2bf(x1.z); a[7] = f2bf(x1.w);
        af[kb] = a;
    }

    const short* wts[3] = {wt0, wt1, wt2};
    bf16* Ys[3] = {Y0, Y1, Y2};

    #pragma unroll
    for (int r = 0; r < R; r++) {
        const short* wrow = wts[r] + (size_t)ncol * IN_F + quad * 8;
        f32x4 acc = {0.f, 0.f, 0.f, 0.f};
        #pragma unroll
        for (int kb = 0; kb < 4; kb++) {
            short8 bfr = *(const short8*)(wrow + kb * 32);
            acc = __builtin_amdgcn_mfma_f32_16x16x32_bf16(af[kb], bfr, acc, 0, 0, 0);
        }
        bf16* Yr = Ys[r];
        #pragma unroll
        for (int reg = 0; reg < 4; reg++) {
            int row = rowBase + quad * 4 + reg;
            Yr[(size_t)row * OUT_F + ncol] = __float2bfloat16(acc[reg]);
        }
    }

    {
        const short* wrow = wtS + (size_t)ncol * IN_F + quad * 8;
        f32x4 acc = {0.f, 0.f, 0.f, 0.f};
        #pragma unroll
        for (int kb = 0; kb < 4; kb++) {
            short8 bfr = *(const short8*)(wrow + kb * 32);
            acc = __builtin_amdgcn_mfma_f32_16x16x32_bf16(af[kb], bfr, acc, 0, 0, 0);
        }
        const float b = bias[ncol];
        #pragma unroll
        for (int reg = 0; reg < 4; reg++) {
            int row = rowBase + quad * 4 + reg;
            OutSelf[(size_t)row * OUT_F + ncol] = acc[reg] + b;
        }
    }
}

// block ranges: paper 12500, author 6250, field 3125, inst 500 -> 22375 total
__global__ __launch_bounds__(256) void proj_all(
    const float* __restrict__ x_author, const float* __restrict__ x_field,
    const float* __restrict__ x_inst,   const float* __restrict__ x_paper,
    const short* __restrict__ wt, const float* __restrict__ bias,
    bf16* __restrict__ y, float* __restrict__ out) {
    int b = blockIdx.x;
    if (b < 12500) {
        projBody<3>(b, x_paper, wt + 1 * 8192, wt + 2 * 8192, wt + 3 * 8192, wt + 7 * 8192,
                    bias, y + YR_RWRITES * OUT_F, y + YR_CITES * OUT_F, y + YR_HTOPIC * OUT_F,
                    out + OUT_PAPER);
    } else if (b < 18750) {
        projBody<2>(b - 12500, x_author, wt + 0 * 8192, wt + 5 * 8192, nullptr, wt + 7 * 8192,
                    bias, y + YR_WRITES * OUT_F, y + YR_AFFIL * OUT_F, nullptr,
                    out + OUT_AUTHOR);
    } else if (b < 21875) {
        projBody<1>(b - 18750, x_field, wt + 4 * 8192, nullptr, nullptr, wt + 7 * 8192,
                    bias, y + YR_RHTOPIC * OUT_F, nullptr, nullptr,
                    out + OUT_FIELD);
    } else {
        projBody<1>(b - 21875, x_inst, wt + 6 * 8192, nullptr, nullptr, wt + 7 * 8192,
                    bias, y + YR_RAFFIL * OUT_F, nullptr, nullptr,
                    out + OUT_INST);
    }
}

// ================= merged gather: 8 lanes/edge, uint4 loads ===================
// lane: g = lane>>3 (edge subgroup 0..7), f = lane&7 (feature octet, 16 B).
// One load instruction fetches 8 edge rows; 2 instructions in flight (16 rows).
// Branch-free: indices clamped to e-1, contribution masked by FMA weight.
// Butterfly xor 8/16/32 combines subgroups; lanes 0..7 RMW 32 B each (+relu).
template <int NR>
__device__ __forceinline__ void gatherNode(
    int n, int lane, const int* __restrict__ csr,
    const int* __restrict__ off0, const uint4* __restrict__ y0,
    const int* __restrict__ off1, const uint4* __restrict__ y1,
    const int* __restrict__ off2, const uint4* __restrict__ y2,
    float* __restrict__ out) {
    const int g = lane >> 3;
    const int f = lane & 7;
    const int* offs[3] = {off0, off1, off2};
    const uint4* ys[3] = {y0, y1, y2};
    float acc[8] = {0.f, 0.f, 0.f, 0.f, 0.f, 0.f, 0.f, 0.f};
    #pragma unroll
    for (int r = 0; r < NR; r++) {
        const int s = offs[r][n];
        const int e = offs[r][n + 1];
        const uint4* __restrict__ yr = ys[r];
        float racc[8] = {0.f, 0.f, 0.f, 0.f, 0.f, 0.f, 0.f, 0.f};
        for (int j = s; j < e; j += 16) {
            int i0 = j + g;
            int i1 = j + 8 + g;
            int c0 = csr[min(i0, e - 1)];
            int c1 = csr[min(i1, e - 1)];
            uint4 u0 = yr[(size_t)c0 * 8 + f];
            uint4 u1 = yr[(size_t)c1 * 8 + f];
            float m0 = (i0 < e) ? 1.f : 0.f;
            float m1 = (i1 < e) ? 1.f : 0.f;
            racc[0] += m0 * bflo(u0.x); racc[1] += m0 * bfhi(u0.x);
            racc[2] += m0 * bflo(u0.y); racc[3] += m0 * bfhi(u0.y);
            racc[4] += m0 * bflo(u0.z); racc[5] += m0 * bfhi(u0.z);
            racc[6] += m0 * bflo(u0.w); racc[7] += m0 * bfhi(u0.w);
            racc[0] += m1 * bflo(u1.x); racc[1] += m1 * bfhi(u1.x);
            racc[2] += m1 * bflo(u1.y); racc[3] += m1 * bfhi(u1.y);
            racc[4] += m1 * bflo(u1.z); racc[5] += m1 * bfhi(u1.z);
            racc[6] += m1 * bflo(u1.w); racc[7] += m1 * bfhi(u1.w);
        }
        int dg = e - s;
        float inv = 1.0f / (float)(dg > 1 ? dg : 1);
        #pragma unroll
        for (int k = 0; k < 8; k++) acc[k] += racc[k] * inv;
    }
    #pragma unroll
    for (int d = 8; d <= 32; d <<= 1) {
        #pragma unroll
        for (int k = 0; k < 8; k++) acc[k] += __shfl_xor(acc[k], d, 64);
    }
    if (lane < 8) {
        float* orow = out + (size_t)n * OUT_F + f * 8;
        float4 c0 = *(float4*)orow;
        float4 c1 = *(float4*)(orow + 4);
        c0.x = fmaxf(c0.x + acc[0], 0.f); c0.y = fmaxf(c0.y + acc[1], 0.f);
        c0.z = fmaxf(c0.z + acc[2], 0.f); c0.w = fmaxf(c0.w + acc[3], 0.f);
        c1.x = fmaxf(c1.x + acc[4], 0.f); c1.y = fmaxf(c1.y + acc[5], 0.f);
        c1.z = fmaxf(c1.z + acc[6], 0.f); c1.w = fmaxf(c1.w + acc[7], 0.f);
        *(float4*)orow = c0;
        *(float4*)(orow + 4) = c1;
    }
}

// block ranges (4 nodes/block): paper 50000, author 25000, field 12500, inst 2000
__global__ __launch_bounds__(256) void gather_all(
    const int* __restrict__ csr, const int* __restrict__ off,
    const bf16* __restrict__ y, float* __restrict__ out) {
    const int b = blockIdx.x;
    const int tid = threadIdx.x;
    const int lane = tid & 63;
    const int wv = tid >> 6;
    if (b < 50000) {
        gatherNode<3>(b * 4 + wv, lane, csr,
                      off + DG_WRITES,  (const uint4*)(y + YR_WRITES * OUT_F),
                      off + DG_CITES,   (const uint4*)(y + YR_CITES * OUT_F),
                      off + DG_RHTOPIC, (const uint4*)(y + YR_RHTOPIC * OUT_F),
                      out + OUT_PAPER);
    } else if (b < 75000) {
        gatherNode<2>((b - 50000) * 4 + wv, lane, csr,
                      off + DG_RWRITES, (const uint4*)(y + YR_RWRITES * OUT_F),
                      off + DG_RAFFIL,  (const uint4*)(y + YR_RAFFIL * OUT_F),
                      nullptr, nullptr,
                      out + OUT_AUTHOR);
    } else if (b < 87500) {
        gatherNode<1>((b - 75000) * 4 + wv, lane, csr,
                      off + DG_HTOPIC, (const uint4*)(y + YR_HTOPIC * OUT_F),
                      nullptr, nullptr, nullptr, nullptr,
                      out + OUT_FIELD);
    } else {
        gatherNode<1>((b - 87500) * 4 + wv, lane, csr,
                      off + DG_AFFIL, (const uint4*)(y + YR_AFFIL * OUT_F),
                      nullptr, nullptr, nullptr, nullptr,
                      out + OUT_INST);
    }
}

extern "C" void kernel_launch(void* const* d_in, const int* in_sizes, int n_in,
                              void* d_out, int out_size, void* d_ws, size_t ws_size,
                              hipStream_t stream) {
    (void)in_sizes; (void)n_in; (void)ws_size; (void)out_size;

    const float* x_author = (const float*)d_in[0];
    const float* x_field  = (const float*)d_in[1];
    const float* x_inst   = (const float*)d_in[2];
    const float* x_paper  = (const float*)d_in[3];
    const float* weight   = (const float*)d_in[4];
    const float* slw      = (const float*)d_in[5];
    const float* bias     = (const float*)d_in[6];
    float* out = (float*)d_out;

    // ---- workspace layout ----
    char* w = (char*)d_ws;
    auto alignup = [](size_t v) { return (v + 127) & ~(size_t)127; };
    bf16* y  = (bf16*)w;              size_t o1 = alignup((size_t)N_NODES * OUT_F * sizeof(bf16));
    int* deg = (int*)(w + o1);        size_t o2 = o1 + alignup((size_t)N_NODES * sizeof(int));
    int* off = (int*)(w + o2);        size_t o3 = o2 + alignup(((size_t)N_NODES + 4) * sizeof(int));
    int* cursor = (int*)(w + o3);     size_t o4 = o3 + alignup((size_t)N_NODES * sizeof(int));
    int* csr = (int*)(w + o4);        size_t o5 = o4 + alignup((size_t)E_TOTAL * sizeof(int));
    int* bsums = (int*)(w + o5);      size_t o6 = o5 + alignup(2048 * sizeof(int));
    short* wt = (short*)(w + o6);

    const int* ws_p[7] = {(const int*)d_in[7],  (const int*)d_in[9],  (const int*)d_in[11],
                          (const int*)d_in[13], (const int*)d_in[15], (const int*)d_in[17],
                          (const int*)d_in[19]};
    const int* wd_p[7] = {(const int*)d_in[8],  (const int*)d_in[10], (const int*)d_in[12],
                          (const int*)d_in[14], (const int*)d_in[16], (const int*)d_in[18],
                          (const int*)d_in[20]};

    const int NBLK = (N_NODES + 1023) / 1024;   // 838

    // 1) W transpose+cast (no deps)
    prep_wt<<<8, 256, 0, stream>>>(weight, slw, wt);

    // 2) degrees
    hipMemsetAsync(deg, 0, (size_t)N_NODES * sizeof(int), stream);
    deg_all<<<19535, 256, 0, stream>>>(wd_p[0], wd_p[1], wd_p[2], wd_p[3],
                                       wd_p[4], wd_p[5], wd_p[6], deg);

    // 3) scan -> off, cursor
    scan1<<<NBLK, 256, 0, stream>>>(deg, off, bsums, N_NODES);
    scan2<<<1, 1024, 0, stream>>>(bsums, NBLK);
    scan3<<<NBLK, 256, 0, stream>>>(off, cursor, bsums, N_NODES, E_TOTAL);

    // 4) CSR fill
    fill_all<<<19535, 256, 0, stream>>>(ws_p[0], wd_p[0], ws_p[1], wd_p[1],
                                        ws_p[2], wd_p[2], ws_p[3], wd_p[3],
                                        ws_p[4], wd_p[4], ws_p[5], wd_p[5],
                                        ws_p[6], wd_p[6], cursor, csr);

    // 5) fused MFMA projections + self-loop init
    proj_all<<<22375, 256, 0, stream>>>(x_author, x_field, x_inst, x_paper,
                                        wt, bias, y, out);

    // 6) fused gather + norm + selfloop-add + relu
    gather_all<<<89500, 256, 0, stream>>>(csr, off, y, out);
}